// Round 15
// baseline (224.545 us; speedup 1.0000x reference)
//
#include <hip/hip_runtime.h>
#include <hip/hip_bf16.h>

typedef unsigned short u16;
typedef __attribute__((ext_vector_type(8))) short short8;
typedef __attribute__((ext_vector_type(2))) float f32x2;
typedef __attribute__((ext_vector_type(4))) float f32x4;
typedef __attribute__((ext_vector_type(16))) float f32x16;

#define N_NODES 4096
#define FIN 512
#define KH 8
#define FO 128
#define DM 1024   // KH*FO
#define LOG2E 1.44269504088896340736f

__device__ __forceinline__ void gload16(const u16* g, u16* l) {
    __builtin_amdgcn_global_load_lds(
        (const __attribute__((address_space(1))) unsigned int*)g,
        (__attribute__((address_space(3))) unsigned int*)l,
        16, 0, 0);
}

__device__ __forceinline__ unsigned pk_bf16(float lo, float hi) {
    unsigned r;
    asm("v_cvt_pk_bf16_f32 %0, %1, %2" : "=v"(r) : "v"(lo), "v"(hi));
    return r;
}

// ---------------- Kernel P: split fp32 -> (hi, lo) bf16 ----------------
__global__ __launch_bounds__(256) void split_bf16(const float* __restrict__ src,
                                                  u16* __restrict__ hi,
                                                  u16* __restrict__ lo,
                                                  int n4) {
    int idx = blockIdx.x * 256 + threadIdx.x;
    if (idx >= n4) return;
    float4 v = ((const float4*)src)[idx];
    unsigned h01 = pk_bf16(v.x, v.y);
    unsigned h23 = pk_bf16(v.z, v.w);
    float hx = __uint_as_float(h01 << 16);
    float hy = __uint_as_float(h01 & 0xffff0000u);
    float hz = __uint_as_float(h23 << 16);
    float hw = __uint_as_float(h23 & 0xffff0000u);
    unsigned l01 = pk_bf16(v.x - hx, v.y - hy);
    unsigned l23 = pk_bf16(v.z - hz, v.w - hw);
    uint2 hv; hv.x = h01; hv.y = h23;
    uint2 lv; lv.x = l01; lv.y = l23;
    ((uint2*)hi)[idx] = hv;
    ((uint2*)lo)[idx] = lv;
}

// ---------------- Kernel A: MFMA split-bf16 GEMM + bias + C/D factor tables + transpose ----
__global__ __launch_bounds__(512) void gemm_mfma(const u16* __restrict__ Xh,
                                                 const u16* __restrict__ Xl,
                                                 const u16* __restrict__ Wh,
                                                 const u16* __restrict__ Wl,
                                                 const float* __restrict__ bias,
                                                 const float* __restrict__ aL,
                                                 const float* __restrict__ aR,
                                                 float2* __restrict__ C2,
                                                 unsigned* __restrict__ D2b,
                                                 u16* __restrict__ HbT) {
    const int khead = blockIdx.x;
    const int n0 = blockIdx.y * 128;
    const int tid = threadIdx.x;
    const int w = tid >> 6, lane = tid & 63;
    const int wr = w >> 1, wc = w & 1;
    const int c = lane & 31, half = lane >> 5;

    __shared__ u16 S[2][16384];

    const int sa = w >> 1;
    const int shv = w & 1;
    const int scl = lane & 3;
    const int ssw = ((lane >> 2) ^ (lane >> 4)) & 3;
    const int sgc = scl ^ ssw;
    const u16* gb; int growbase;
    if (sa == 0)      { gb = Xh; growbase = n0; }
    else if (sa == 1) { gb = Xl; growbase = n0; }
    else if (sa == 2) { gb = Wh; growbase = khead * 128; }
    else              { gb = Wl; growbase = khead * 128; }
    const u16* glb = gb + (size_t)(growbase + shv * 64 + (lane >> 2)) * FIN + sgc * 8;
    const int sldsoff = sa * 4096 + shv * 64 * 32;

    const int sw = ((c) ^ (c >> 2)) & 3;
    const int aoff = (wr * 32 + c) * 32;
    const int boff0 = 8192 + (wc * 64 + c) * 32;
    const int boff1 = 8192 + (wc * 64 + 32 + c) * 32;

    f32x16 acc0, acc1;
#pragma unroll
    for (int i = 0; i < 16; ++i) { acc0[i] = 0.f; acc1[i] = 0.f; }

#pragma unroll
    for (int i = 0; i < 4; ++i)
        gload16(glb + (size_t)i * 16 * FIN, &S[0][sldsoff + i * 512]);
    __syncthreads();

    int cur = 0;
    for (int kt = 0; kt < 16; ++kt) {
        if (kt < 15) {
            const u16* gsrc = glb + (kt + 1) * 32;
            u16* dst = &S[cur ^ 1][sldsoff];
#pragma unroll
            for (int i = 0; i < 4; ++i)
                gload16(gsrc + (size_t)i * 16 * FIN, dst + i * 512);
        }

        const u16* sp = S[cur];
        short8 ah[2], al8[2], bh[2][2], bl8[2][2];
#pragma unroll
        for (int ks = 0; ks < 2; ++ks) {
            int ch = ((ks * 2 + half) ^ sw) * 8;
            ah[ks]     = *(const short8*)&sp[aoff + ch];
            al8[ks]    = *(const short8*)&sp[4096 + aoff + ch];
            bh[0][ks]  = *(const short8*)&sp[boff0 + ch];
            bl8[0][ks] = *(const short8*)&sp[boff0 + 4096 + ch];
            bh[1][ks]  = *(const short8*)&sp[boff1 + ch];
            bl8[1][ks] = *(const short8*)&sp[boff1 + 4096 + ch];
        }
#pragma unroll
        for (int ks = 0; ks < 2; ++ks) {
            acc0 = __builtin_amdgcn_mfma_f32_32x32x16_bf16(ah[ks], bh[0][ks], acc0, 0, 0, 0);
            acc0 = __builtin_amdgcn_mfma_f32_32x32x16_bf16(ah[ks], bl8[0][ks], acc0, 0, 0, 0);
            acc0 = __builtin_amdgcn_mfma_f32_32x32x16_bf16(al8[ks], bh[0][ks], acc0, 0, 0, 0);
            acc1 = __builtin_amdgcn_mfma_f32_32x32x16_bf16(ah[ks], bh[1][ks], acc1, 0, 0, 0);
            acc1 = __builtin_amdgcn_mfma_f32_32x32x16_bf16(ah[ks], bl8[1][ks], acc1, 0, 0, 0);
            acc1 = __builtin_amdgcn_mfma_f32_32x32x16_bf16(al8[ks], bh[1][ks], acc1, 0, 0, 0);
        }
        __syncthreads();
        cur ^= 1;
    }

    const int fglob = khead * FO + wc * 64 + c;
    float b0 = bias[fglob], b1 = bias[fglob + 32];
#pragma unroll
    for (int r = 0; r < 16; ++r) { acc0[r] += b0; acc1[r] += b1; }

    float alv0 = aL[fglob], alv1 = aL[fglob + 32];
    float arv0 = aR[fglob], arv1 = aR[fglob + 32];
    float pl[16], pr[16];
#pragma unroll
    for (int r = 0; r < 16; ++r) {
        pl[r] = acc0[r] * alv0 + acc1[r] * alv1;
        pr[r] = acc0[r] * arv0 + acc1[r] * arv1;
    }
#pragma unroll
    for (int off = 1; off < 32; off <<= 1) {
#pragma unroll
        for (int r = 0; r < 16; ++r) {
            pl[r] += __shfl_xor(pl[r], off);
            pr[r] += __shfl_xor(pr[r], off);
        }
    }

    u16* T = &S[0][0];
    float* LRf = (float*)&S[0][0] + 9216;

    if (c == 0) {
#pragma unroll
        for (int r = 0; r < 16; ++r) {
            int node = wr * 32 + (r & 3) + 8 * (r >> 2) + 4 * half;
            LRf[(wc * 2 + 0) * 128 + node] = pl[r];
            LRf[(wc * 2 + 1) * 128 + node] = pr[r];
        }
    }

#pragma unroll
    for (int q = 0; q < 4; ++q) {
        int nb = wr * 32 + q * 8 + 4 * half;
        unsigned p00 = pk_bf16(acc0[q * 4 + 0], acc0[q * 4 + 1]);
        unsigned p01 = pk_bf16(acc0[q * 4 + 2], acc0[q * 4 + 3]);
        unsigned p10 = pk_bf16(acc1[q * 4 + 0], acc1[q * 4 + 1]);
        unsigned p11 = pk_bf16(acc1[q * 4 + 2], acc1[q * 4 + 3]);
        *(unsigned*)&T[(wc * 64 + c) * 136 + nb]      = p00;
        *(unsigned*)&T[(wc * 64 + c) * 136 + nb + 2]  = p01;
        *(unsigned*)&T[(wc * 64 + 32 + c) * 136 + nb]     = p10;
        *(unsigned*)&T[(wc * 64 + 32 + c) * 136 + nb + 2] = p11;
    }
    __syncthreads();

    // factor tables: C2 = (exp2(L2E*l), exp2(0.2*L2E*l)) fp32; D2b = packed bf16 pair
    if (wc == 0) {
        int node = wr * 32 + (lane & 31);
        if (lane < 32) {
            float L = (LRf[0 * 128 + node] + LRf[2 * 128 + node]) * LOG2E;
            float2 cv; cv.x = exp2f(L); cv.y = exp2f(0.2f * L);
            C2[(size_t)khead * N_NODES + n0 + node] = cv;
        } else {
            float R = (LRf[1 * 128 + node] + LRf[3 * 128 + node]) * LOG2E;
            D2b[(size_t)khead * N_NODES + n0 + node] = pk_bf16(exp2f(R), exp2f(0.2f * R));
        }
    }

    {
        int f = tid >> 2, q = tid & 3;
        const uint4* src = (const uint4*)&T[f * 136 + q * 32];
        uint4* dst = (uint4*)(HbT + (size_t)(khead * FO + f) * N_NODES + n0 + q * 32);
#pragma unroll
        for (int u = 0; u < 4; ++u) dst[u] = src[u];
    }
}

// ---------------- Kernel D: pack mask (int32 0/1) into bitmask ----------------
__global__ __launch_bounds__(256) void pack_mask(const int* __restrict__ mask,
                                                 unsigned long long* __restrict__ mb) {
    int gid = blockIdx.x * 256 + threadIdx.x;
    int wid = gid >> 6, lane = gid & 63;
    int v = mask[(size_t)wid * 64 + lane];
    unsigned long long bits = __ballot(v != 0);
    if (lane == 0) mb[wid] = bits;
}

// P-fragment gen: 8 masked leaky-exp values -> short8 (bf16), R11-identical numerics.
__device__ __forceinline__ short8 pgen8(float cx, float cy, uint4 w0, uint4 w1,
                                        unsigned m32) {
    unsigned wa[8] = {w0.x, w0.y, w0.z, w0.w, w1.x, w1.y, w1.z, w1.w};
    union { unsigned u[4]; short8 s; } r;
#pragma unroll
    for (int vp = 0; vp < 4; ++vp) {
        unsigned u0 = wa[2 * vp], u1 = wa[2 * vp + 1];
        float pa = fmaxf(cx * __uint_as_float(u0 << 16),
                         cy * __uint_as_float(u0 & 0xffff0000u));
        float pb = fmaxf(cx * __uint_as_float(u1 << 16),
                         cy * __uint_as_float(u1 & 0xffff0000u));
        unsigned sa = (unsigned)(((int)(m32 << (31 - 2 * vp))) >> 31);
        unsigned sb = (unsigned)(((int)(m32 << (30 - 2 * vp))) >> 31);
        r.u[vp] = pk_bf16(__uint_as_float(__float_as_uint(pa) & sa),
                          __uint_as_float(__float_as_uint(pb) & sb));
    }
    return r.s;
}

// ---------------- Kernel C: BARRIER-FREE masked softmax + PV aggregation ----------------
// No LDS staging: B-fragments read directly from L2 (HbT slice is 1 MB/head,
// XCD-pinned -> L2-resident). 8 waves = ns(2 x 32-row) x mq(4 x 1024-m quarter),
// each wave fully independent for its whole 16-tile loop: per 64-m tile
// {4 D-uint4 + 2 mask-u64 + 4 pgen + 16 direct B-loads + 36 MFMAs}. Zero barriers
// until the final 4-way combine through a 36 KB LDS buffer.
__global__ __launch_bounds__(512, 4) void gat_attn(const u16* __restrict__ HbT,
                                                   const float2* __restrict__ C2,
                                                   const unsigned* __restrict__ D2b,
                                                   const unsigned long long* __restrict__ mb,
                                                   float* __restrict__ out) {
    const int blk = blockIdx.x;
    const int k = blk & 7;
    const int n0 = (blk >> 3) * 64;
    const int tid = threadIdx.x;
    const int w = tid >> 6, lane = tid & 63;
    const int ns = w & 1, mq = w >> 1;
    const int fr = lane & 15, kg = lane >> 4;

    __shared__ float fb[9216];   // 36 KB combine buffer

    const int na0 = n0 + ns * 32 + fr;
    const int na1 = na0 + 16;
    const float2 c0f = C2[(size_t)k * N_NODES + na0];
    const float2 c1f = C2[(size_t)k * N_NODES + na1];
    const float cx0 = c0f.x, cy0 = c0f.y;
    const float cx1 = c1f.x, cy1 = c1f.y;
    const unsigned long long* mrow0 = mb + (size_t)na0 * 64 + mq * 16;
    const unsigned long long* mrow1 = mb + (size_t)na1 * 64 + mq * 16;

    f32x4 acc[2][9];
#pragma unroll
    for (int s = 0; s < 2; ++s)
#pragma unroll
        for (int c = 0; c < 9; ++c) acc[s][c] = 0.f;

    const short o1 = (fr == 0) ? (short)0x3F80 : (short)0;
    const short8 ones = {o1, o1, o1, o1, o1, o1, o1, o1};

    // per-lane bases: B rows (c*16+fr) of head k, this lane's m-chunk in quarter mq
    const u16* bbase = HbT + (size_t)(k * FO + fr) * N_NODES + mq * 1024 + kg * 8;
    const unsigned* D2k = D2b + (size_t)k * N_NODES + mq * 1024 + kg * 8;
    const int shA = kg * 8, shB = shA + 32;

    for (int t = 0; t < 16; ++t) {
        const int m0 = t * 64;
        const unsigned* dp = D2k + m0;
        uint4 dA0 = *(const uint4*)(dp);
        uint4 dA1 = *(const uint4*)(dp + 4);
        uint4 dB0 = *(const uint4*)(dp + 32);
        uint4 dB1 = *(const uint4*)(dp + 36);
        unsigned long long bits0 = mrow0[t];
        unsigned long long bits1 = mrow1[t];

        short8 aA0 = pgen8(cx0, cy0, dA0, dA1, (unsigned)(bits0 >> shA));
        short8 aB0 = pgen8(cx0, cy0, dB0, dB1, (unsigned)(bits0 >> shB));
        short8 aA1 = pgen8(cx1, cy1, dA0, dA1, (unsigned)(bits1 >> shA));
        short8 aB1 = pgen8(cx1, cy1, dB0, dB1, (unsigned)(bits1 >> shB));

        const u16* bp = bbase + m0;
#pragma unroll
        for (int c = 0; c < 8; ++c) {
            short8 bA = *(const short8*)(bp + (size_t)c * 16 * N_NODES);
            short8 bB = *(const short8*)(bp + (size_t)c * 16 * N_NODES + 32);
            acc[0][c] = __builtin_amdgcn_mfma_f32_16x16x32_bf16(aA0, bA, acc[0][c], 0, 0, 0);
            acc[0][c] = __builtin_amdgcn_mfma_f32_16x16x32_bf16(aB0, bB, acc[0][c], 0, 0, 0);
            acc[1][c] = __builtin_amdgcn_mfma_f32_16x16x32_bf16(aA1, bA, acc[1][c], 0, 0, 0);
            acc[1][c] = __builtin_amdgcn_mfma_f32_16x16x32_bf16(aB1, bB, acc[1][c], 0, 0, 0);
        }
        acc[0][8] = __builtin_amdgcn_mfma_f32_16x16x32_bf16(aA0, ones, acc[0][8], 0, 0, 0);
        acc[0][8] = __builtin_amdgcn_mfma_f32_16x16x32_bf16(aB0, ones, acc[0][8], 0, 0, 0);
        acc[1][8] = __builtin_amdgcn_mfma_f32_16x16x32_bf16(aA1, ones, acc[1][8], 0, 0, 0);
        acc[1][8] = __builtin_amdgcn_mfma_f32_16x16x32_bf16(aB1, ones, acc[1][8], 0, 0, 0);
    }

    // ---- 4-way combine over mq: 3 rounds, receiver = mq==0 ----
    const int cb = ns * 4608 + lane;
    for (int src = 1; src < 4; ++src) {
        if (mq == src) {
#pragma unroll
            for (int s = 0; s < 2; ++s)
#pragma unroll
                for (int c = 0; c < 9; ++c)
#pragma unroll
                    for (int j = 0; j < 4; ++j)
                        fb[cb + (((s * 9 + c) * 4 + j) << 6)] = acc[s][c][j];
        }
        __syncthreads();
        if (mq == 0) {
#pragma unroll
            for (int s = 0; s < 2; ++s)
#pragma unroll
                for (int c = 0; c < 9; ++c)
#pragma unroll
                    for (int j = 0; j < 4; ++j)
                        acc[s][c][j] += fb[cb + (((s * 9 + c) * 4 + j) << 6)];
        }
        __syncthreads();
    }

    // ---- epilogue (receiver waves): divide by S, ELU, store ----
    if (mq == 0) {
#pragma unroll
        for (int s = 0; s < 2; ++s) {
#pragma unroll
            for (int j = 0; j < 4; ++j) {
                float S = __shfl(acc[s][8][j], (lane & 48));
                float inv = 1.0f / S;
                int n_out = n0 + ns * 32 + s * 16 + kg * 4 + j;
                float* orow = out + (size_t)n_out * DM + k * FO + fr;
#pragma unroll
                for (int c = 0; c < 8; ++c) {
                    float v = acc[s][c][j] * inv;
                    float e = v > 0.f ? v : (__expf(v) - 1.0f);
                    orow[c * 16] = e;
                }
            }
        }
    }
}

extern "C" void kernel_launch(void* const* d_in, const int* in_sizes, int n_in,
                              void* d_out, int out_size, void* d_ws, size_t ws_size,
                              hipStream_t stream) {
    const float* x = (const float*)d_in[0];
    const int* mask = (const int*)d_in[1];
    const float* W = (const float*)d_in[2];
    const float* bias = (const float*)d_in[3];
    const float* aL = (const float*)d_in[4];
    const float* aR = (const float*)d_in[5];
    float* out = (float*)d_out;

    char* ws = (char*)d_ws;
    u16* Xh = (u16*)ws;   ws += (size_t)N_NODES * FIN * 2;   // 4.19 MB
    u16* Xl = (u16*)ws;   ws += (size_t)N_NODES * FIN * 2;   // 4.19 MB
    u16* Wh = (u16*)ws;   ws += (size_t)DM * FIN * 2;        // 1.05 MB
    u16* Wl = (u16*)ws;   ws += (size_t)DM * FIN * 2;        // 1.05 MB
    u16* HbT = (u16*)ws;  ws += (size_t)KH * FO * N_NODES * 2; // 8.39 MB
    float2* C2 = (float2*)ws;  ws += (size_t)KH * N_NODES * 8;  // 256 KB
    unsigned* D2b = (unsigned*)ws; ws += (size_t)KH * N_NODES * 4; // 128 KB
    unsigned long long* mb = (unsigned long long*)ws;        // 2 MB

    split_bf16<<<dim3(2048), dim3(256), 0, stream>>>(x, Xh, Xl, N_NODES * FIN / 4);
    split_bf16<<<dim3(512), dim3(256), 0, stream>>>(W, Wh, Wl, DM * FIN / 4);
    gemm_mfma<<<dim3(8, 32), dim3(512), 0, stream>>>(Xh, Xl, Wh, Wl, bias, aL, aR,
                                                     C2, D2b, HbT);
    pack_mask<<<dim3(65536), dim3(256), 0, stream>>>(mask, mb);
    gat_attn<<<dim3(512), dim3(512), 0, stream>>>(HbT, C2, D2b, mb, out);
}

// Round 16
// 218.190 us; speedup vs baseline: 1.0291x; 1.0291x over previous
//
#include <hip/hip_runtime.h>
#include <hip/hip_bf16.h>

typedef unsigned short u16;
typedef __attribute__((ext_vector_type(8))) short short8;
typedef __attribute__((ext_vector_type(2))) float f32x2;
typedef __attribute__((ext_vector_type(4))) float f32x4;
typedef __attribute__((ext_vector_type(16))) float f32x16;

#define N_NODES 4096
#define FIN 512
#define KH 8
#define FO 128
#define DM 1024   // KH*FO
#define LOG2E 1.44269504088896340736f

__device__ __forceinline__ void gload16(const u16* g, u16* l) {
    __builtin_amdgcn_global_load_lds(
        (const __attribute__((address_space(1))) unsigned int*)g,
        (__attribute__((address_space(3))) unsigned int*)l,
        16, 0, 0);
}

__device__ __forceinline__ unsigned pk_bf16(float lo, float hi) {
    unsigned r;
    asm("v_cvt_pk_bf16_f32 %0, %1, %2" : "=v"(r) : "v"(lo), "v"(hi));
    return r;
}

// ---------------- Kernel P: split fp32 -> (hi, lo) bf16 ----------------
__global__ __launch_bounds__(256) void split_bf16(const float* __restrict__ src,
                                                  u16* __restrict__ hi,
                                                  u16* __restrict__ lo,
                                                  int n4) {
    int idx = blockIdx.x * 256 + threadIdx.x;
    if (idx >= n4) return;
    float4 v = ((const float4*)src)[idx];
    unsigned h01 = pk_bf16(v.x, v.y);
    unsigned h23 = pk_bf16(v.z, v.w);
    float hx = __uint_as_float(h01 << 16);
    float hy = __uint_as_float(h01 & 0xffff0000u);
    float hz = __uint_as_float(h23 << 16);
    float hw = __uint_as_float(h23 & 0xffff0000u);
    unsigned l01 = pk_bf16(v.x - hx, v.y - hy);
    unsigned l23 = pk_bf16(v.z - hz, v.w - hw);
    uint2 hv; hv.x = h01; hv.y = h23;
    uint2 lv; lv.x = l01; lv.y = l23;
    ((uint2*)hi)[idx] = hv;
    ((uint2*)lo)[idx] = lv;
}

// ---------------- Kernel A: MFMA split-bf16 GEMM + bias + C/D factor tables + transpose ----
__global__ __launch_bounds__(512) void gemm_mfma(const u16* __restrict__ Xh,
                                                 const u16* __restrict__ Xl,
                                                 const u16* __restrict__ Wh,
                                                 const u16* __restrict__ Wl,
                                                 const float* __restrict__ bias,
                                                 const float* __restrict__ aL,
                                                 const float* __restrict__ aR,
                                                 float2* __restrict__ C2,
                                                 unsigned* __restrict__ D2b,
                                                 u16* __restrict__ HbT) {
    const int khead = blockIdx.x;
    const int n0 = blockIdx.y * 128;
    const int tid = threadIdx.x;
    const int w = tid >> 6, lane = tid & 63;
    const int wr = w >> 1, wc = w & 1;
    const int c = lane & 31, half = lane >> 5;

    __shared__ u16 S[2][16384];

    const int sa = w >> 1;
    const int shv = w & 1;
    const int scl = lane & 3;
    const int ssw = ((lane >> 2) ^ (lane >> 4)) & 3;
    const int sgc = scl ^ ssw;
    const u16* gb; int growbase;
    if (sa == 0)      { gb = Xh; growbase = n0; }
    else if (sa == 1) { gb = Xl; growbase = n0; }
    else if (sa == 2) { gb = Wh; growbase = khead * 128; }
    else              { gb = Wl; growbase = khead * 128; }
    const u16* glb = gb + (size_t)(growbase + shv * 64 + (lane >> 2)) * FIN + sgc * 8;
    const int sldsoff = sa * 4096 + shv * 64 * 32;

    const int sw = ((c) ^ (c >> 2)) & 3;
    const int aoff = (wr * 32 + c) * 32;
    const int boff0 = 8192 + (wc * 64 + c) * 32;
    const int boff1 = 8192 + (wc * 64 + 32 + c) * 32;

    f32x16 acc0, acc1;
#pragma unroll
    for (int i = 0; i < 16; ++i) { acc0[i] = 0.f; acc1[i] = 0.f; }

#pragma unroll
    for (int i = 0; i < 4; ++i)
        gload16(glb + (size_t)i * 16 * FIN, &S[0][sldsoff + i * 512]);
    __syncthreads();

    int cur = 0;
    for (int kt = 0; kt < 16; ++kt) {
        if (kt < 15) {
            const u16* gsrc = glb + (kt + 1) * 32;
            u16* dst = &S[cur ^ 1][sldsoff];
#pragma unroll
            for (int i = 0; i < 4; ++i)
                gload16(gsrc + (size_t)i * 16 * FIN, dst + i * 512);
        }

        const u16* sp = S[cur];
        short8 ah[2], al8[2], bh[2][2], bl8[2][2];
#pragma unroll
        for (int ks = 0; ks < 2; ++ks) {
            int ch = ((ks * 2 + half) ^ sw) * 8;
            ah[ks]     = *(const short8*)&sp[aoff + ch];
            al8[ks]    = *(const short8*)&sp[4096 + aoff + ch];
            bh[0][ks]  = *(const short8*)&sp[boff0 + ch];
            bl8[0][ks] = *(const short8*)&sp[boff0 + 4096 + ch];
            bh[1][ks]  = *(const short8*)&sp[boff1 + ch];
            bl8[1][ks] = *(const short8*)&sp[boff1 + 4096 + ch];
        }
#pragma unroll
        for (int ks = 0; ks < 2; ++ks) {
            acc0 = __builtin_amdgcn_mfma_f32_32x32x16_bf16(ah[ks], bh[0][ks], acc0, 0, 0, 0);
            acc0 = __builtin_amdgcn_mfma_f32_32x32x16_bf16(ah[ks], bl8[0][ks], acc0, 0, 0, 0);
            acc0 = __builtin_amdgcn_mfma_f32_32x32x16_bf16(al8[ks], bh[0][ks], acc0, 0, 0, 0);
            acc1 = __builtin_amdgcn_mfma_f32_32x32x16_bf16(ah[ks], bh[1][ks], acc1, 0, 0, 0);
            acc1 = __builtin_amdgcn_mfma_f32_32x32x16_bf16(ah[ks], bl8[1][ks], acc1, 0, 0, 0);
            acc1 = __builtin_amdgcn_mfma_f32_32x32x16_bf16(al8[ks], bh[1][ks], acc1, 0, 0, 0);
        }
        __syncthreads();
        cur ^= 1;
    }

    const int fglob = khead * FO + wc * 64 + c;
    float b0 = bias[fglob], b1 = bias[fglob + 32];
#pragma unroll
    for (int r = 0; r < 16; ++r) { acc0[r] += b0; acc1[r] += b1; }

    float alv0 = aL[fglob], alv1 = aL[fglob + 32];
    float arv0 = aR[fglob], arv1 = aR[fglob + 32];
    float pl[16], pr[16];
#pragma unroll
    for (int r = 0; r < 16; ++r) {
        pl[r] = acc0[r] * alv0 + acc1[r] * alv1;
        pr[r] = acc0[r] * arv0 + acc1[r] * arv1;
    }
#pragma unroll
    for (int off = 1; off < 32; off <<= 1) {
#pragma unroll
        for (int r = 0; r < 16; ++r) {
            pl[r] += __shfl_xor(pl[r], off);
            pr[r] += __shfl_xor(pr[r], off);
        }
    }

    u16* T = &S[0][0];
    float* LRf = (float*)&S[0][0] + 9216;

    if (c == 0) {
#pragma unroll
        for (int r = 0; r < 16; ++r) {
            int node = wr * 32 + (r & 3) + 8 * (r >> 2) + 4 * half;
            LRf[(wc * 2 + 0) * 128 + node] = pl[r];
            LRf[(wc * 2 + 1) * 128 + node] = pr[r];
        }
    }

#pragma unroll
    for (int q = 0; q < 4; ++q) {
        int nb = wr * 32 + q * 8 + 4 * half;
        unsigned p00 = pk_bf16(acc0[q * 4 + 0], acc0[q * 4 + 1]);
        unsigned p01 = pk_bf16(acc0[q * 4 + 2], acc0[q * 4 + 3]);
        unsigned p10 = pk_bf16(acc1[q * 4 + 0], acc1[q * 4 + 1]);
        unsigned p11 = pk_bf16(acc1[q * 4 + 2], acc1[q * 4 + 3]);
        *(unsigned*)&T[(wc * 64 + c) * 136 + nb]      = p00;
        *(unsigned*)&T[(wc * 64 + c) * 136 + nb + 2]  = p01;
        *(unsigned*)&T[(wc * 64 + 32 + c) * 136 + nb]     = p10;
        *(unsigned*)&T[(wc * 64 + 32 + c) * 136 + nb + 2] = p11;
    }
    __syncthreads();

    // factor tables: C2 = (exp2(L2E*l), exp2(0.2*L2E*l)) fp32; D2b = packed bf16 pair
    if (wc == 0) {
        int node = wr * 32 + (lane & 31);
        if (lane < 32) {
            float L = (LRf[0 * 128 + node] + LRf[2 * 128 + node]) * LOG2E;
            float2 cv; cv.x = exp2f(L); cv.y = exp2f(0.2f * L);
            C2[(size_t)khead * N_NODES + n0 + node] = cv;
        } else {
            float R = (LRf[1 * 128 + node] + LRf[3 * 128 + node]) * LOG2E;
            D2b[(size_t)khead * N_NODES + n0 + node] = pk_bf16(exp2f(R), exp2f(0.2f * R));
        }
    }

    {
        int f = tid >> 2, q = tid & 3;
        const uint4* src = (const uint4*)&T[f * 136 + q * 32];
        uint4* dst = (uint4*)(HbT + (size_t)(khead * FO + f) * N_NODES + n0 + q * 32);
#pragma unroll
        for (int u = 0; u < 4; ++u) dst[u] = src[u];
    }
}

// ---------------- Kernel D: pack mask (int32 0/1) into bitmask ----------------
__global__ __launch_bounds__(256) void pack_mask(const int* __restrict__ mask,
                                                 unsigned long long* __restrict__ mb) {
    int gid = blockIdx.x * 256 + threadIdx.x;
    int wid = gid >> 6, lane = gid & 63;
    int v = mask[(size_t)wid * 64 + lane];
    unsigned long long bits = __ballot(v != 0);
    if (lane == 0) mb[wid] = bits;
}

// P-fragment gen: 8 masked leaky-exp values -> short8 (bf16), R11-identical numerics.
__device__ __forceinline__ short8 pgen8(float cx, float cy, uint4 w0, uint4 w1,
                                        unsigned m32) {
    unsigned wa[8] = {w0.x, w0.y, w0.z, w0.w, w1.x, w1.y, w1.z, w1.w};
    union { unsigned u[4]; short8 s; } r;
#pragma unroll
    for (int vp = 0; vp < 4; ++vp) {
        unsigned u0 = wa[2 * vp], u1 = wa[2 * vp + 1];
        float pa = fmaxf(cx * __uint_as_float(u0 << 16),
                         cy * __uint_as_float(u0 & 0xffff0000u));
        float pb = fmaxf(cx * __uint_as_float(u1 << 16),
                         cy * __uint_as_float(u1 & 0xffff0000u));
        unsigned sa = (unsigned)(((int)(m32 << (31 - 2 * vp))) >> 31);
        unsigned sb = (unsigned)(((int)(m32 << (30 - 2 * vp))) >> 31);
        r.u[vp] = pk_bf16(__uint_as_float(__float_as_uint(pa) & sa),
                          __uint_as_float(__float_as_uint(pb) & sb));
    }
    return r.s;
}

// ---------------- Kernel C: BARRIER-FREE masked softmax + PV aggregation ----------------
// Identical to R15 except __launch_bounds__(512, 2): R15's (512,4) capped VGPRs at a
// level where the 72-register accumulator spilled to scratch (92 MB of scratch writes,
// VALUBusy 18%). (512,2) gives the 256-VGPR budget; waves are barrier-free and
// independent, so 16 free-slipping waves/CU provide the latency hiding.
__global__ __launch_bounds__(512, 2) void gat_attn(const u16* __restrict__ HbT,
                                                   const float2* __restrict__ C2,
                                                   const unsigned* __restrict__ D2b,
                                                   const unsigned long long* __restrict__ mb,
                                                   float* __restrict__ out) {
    const int blk = blockIdx.x;
    const int k = blk & 7;
    const int n0 = (blk >> 3) * 64;
    const int tid = threadIdx.x;
    const int w = tid >> 6, lane = tid & 63;
    const int ns = w & 1, mq = w >> 1;
    const int fr = lane & 15, kg = lane >> 4;

    __shared__ float fb[9216];   // 36 KB combine buffer

    const int na0 = n0 + ns * 32 + fr;
    const int na1 = na0 + 16;
    const float2 c0f = C2[(size_t)k * N_NODES + na0];
    const float2 c1f = C2[(size_t)k * N_NODES + na1];
    const float cx0 = c0f.x, cy0 = c0f.y;
    const float cx1 = c1f.x, cy1 = c1f.y;
    const unsigned long long* mrow0 = mb + (size_t)na0 * 64 + mq * 16;
    const unsigned long long* mrow1 = mb + (size_t)na1 * 64 + mq * 16;

    f32x4 acc[2][9];
#pragma unroll
    for (int s = 0; s < 2; ++s)
#pragma unroll
        for (int c = 0; c < 9; ++c) acc[s][c] = 0.f;

    const short o1 = (fr == 0) ? (short)0x3F80 : (short)0;
    const short8 ones = {o1, o1, o1, o1, o1, o1, o1, o1};

    // per-lane bases: B rows (c*16+fr) of head k, this lane's m-chunk in quarter mq
    const u16* bbase = HbT + (size_t)(k * FO + fr) * N_NODES + mq * 1024 + kg * 8;
    const unsigned* D2k = D2b + (size_t)k * N_NODES + mq * 1024 + kg * 8;
    const int shA = kg * 8, shB = shA + 32;

    for (int t = 0; t < 16; ++t) {
        const int m0 = t * 64;
        const unsigned* dp = D2k + m0;
        uint4 dA0 = *(const uint4*)(dp);
        uint4 dA1 = *(const uint4*)(dp + 4);
        uint4 dB0 = *(const uint4*)(dp + 32);
        uint4 dB1 = *(const uint4*)(dp + 36);
        unsigned long long bits0 = mrow0[t];
        unsigned long long bits1 = mrow1[t];

        short8 aA0 = pgen8(cx0, cy0, dA0, dA1, (unsigned)(bits0 >> shA));
        short8 aB0 = pgen8(cx0, cy0, dB0, dB1, (unsigned)(bits0 >> shB));
        short8 aA1 = pgen8(cx1, cy1, dA0, dA1, (unsigned)(bits1 >> shA));
        short8 aB1 = pgen8(cx1, cy1, dB0, dB1, (unsigned)(bits1 >> shB));

        const u16* bp = bbase + m0;
#pragma unroll
        for (int c = 0; c < 8; ++c) {
            short8 bA = *(const short8*)(bp + (size_t)c * 16 * N_NODES);
            short8 bB = *(const short8*)(bp + (size_t)c * 16 * N_NODES + 32);
            acc[0][c] = __builtin_amdgcn_mfma_f32_16x16x32_bf16(aA0, bA, acc[0][c], 0, 0, 0);
            acc[0][c] = __builtin_amdgcn_mfma_f32_16x16x32_bf16(aB0, bB, acc[0][c], 0, 0, 0);
            acc[1][c] = __builtin_amdgcn_mfma_f32_16x16x32_bf16(aA1, bA, acc[1][c], 0, 0, 0);
            acc[1][c] = __builtin_amdgcn_mfma_f32_16x16x32_bf16(aB1, bB, acc[1][c], 0, 0, 0);
        }
        acc[0][8] = __builtin_amdgcn_mfma_f32_16x16x32_bf16(aA0, ones, acc[0][8], 0, 0, 0);
        acc[0][8] = __builtin_amdgcn_mfma_f32_16x16x32_bf16(aB0, ones, acc[0][8], 0, 0, 0);
        acc[1][8] = __builtin_amdgcn_mfma_f32_16x16x32_bf16(aA1, ones, acc[1][8], 0, 0, 0);
        acc[1][8] = __builtin_amdgcn_mfma_f32_16x16x32_bf16(aB1, ones, acc[1][8], 0, 0, 0);
    }

    // ---- 4-way combine over mq: 3 rounds, receiver = mq==0 ----
    const int cb = ns * 4608 + lane;
    for (int src = 1; src < 4; ++src) {
        if (mq == src) {
#pragma unroll
            for (int s = 0; s < 2; ++s)
#pragma unroll
                for (int c = 0; c < 9; ++c)
#pragma unroll
                    for (int j = 0; j < 4; ++j)
                        fb[cb + (((s * 9 + c) * 4 + j) << 6)] = acc[s][c][j];
        }
        __syncthreads();
        if (mq == 0) {
#pragma unroll
            for (int s = 0; s < 2; ++s)
#pragma unroll
                for (int c = 0; c < 9; ++c)
#pragma unroll
                    for (int j = 0; j < 4; ++j)
                        acc[s][c][j] += fb[cb + (((s * 9 + c) * 4 + j) << 6)];
        }
        __syncthreads();
    }

    // ---- epilogue (receiver waves): divide by S, ELU, store ----
    if (mq == 0) {
#pragma unroll
        for (int s = 0; s < 2; ++s) {
#pragma unroll
            for (int j = 0; j < 4; ++j) {
                float S = __shfl(acc[s][8][j], (lane & 48));
                float inv = 1.0f / S;
                int n_out = n0 + ns * 32 + s * 16 + kg * 4 + j;
                float* orow = out + (size_t)n_out * DM + k * FO + fr;
#pragma unroll
                for (int c = 0; c < 8; ++c) {
                    float v = acc[s][c][j] * inv;
                    float e = v > 0.f ? v : (__expf(v) - 1.0f);
                    orow[c * 16] = e;
                }
            }
        }
    }
}

extern "C" void kernel_launch(void* const* d_in, const int* in_sizes, int n_in,
                              void* d_out, int out_size, void* d_ws, size_t ws_size,
                              hipStream_t stream) {
    const float* x = (const float*)d_in[0];
    const int* mask = (const int*)d_in[1];
    const float* W = (const float*)d_in[2];
    const float* bias = (const float*)d_in[3];
    const float* aL = (const float*)d_in[4];
    const float* aR = (const float*)d_in[5];
    float* out = (float*)d_out;

    char* ws = (char*)d_ws;
    u16* Xh = (u16*)ws;   ws += (size_t)N_NODES * FIN * 2;   // 4.19 MB
    u16* Xl = (u16*)ws;   ws += (size_t)N_NODES * FIN * 2;   // 4.19 MB
    u16* Wh = (u16*)ws;   ws += (size_t)DM * FIN * 2;        // 1.05 MB
    u16* Wl = (u16*)ws;   ws += (size_t)DM * FIN * 2;        // 1.05 MB
    u16* HbT = (u16*)ws;  ws += (size_t)KH * FO * N_NODES * 2; // 8.39 MB
    float2* C2 = (float2*)ws;  ws += (size_t)KH * N_NODES * 8;  // 256 KB
    unsigned* D2b = (unsigned*)ws; ws += (size_t)KH * N_NODES * 4; // 128 KB
    unsigned long long* mb = (unsigned long long*)ws;        // 2 MB

    split_bf16<<<dim3(2048), dim3(256), 0, stream>>>(x, Xh, Xl, N_NODES * FIN / 4);
    split_bf16<<<dim3(512), dim3(256), 0, stream>>>(W, Wh, Wl, DM * FIN / 4);
    gemm_mfma<<<dim3(8, 32), dim3(512), 0, stream>>>(Xh, Xl, Wh, Wl, bias, aL, aR,
                                                     C2, D2b, HbT);
    pack_mask<<<dim3(65536), dim3(256), 0, stream>>>(mask, mb);
    gat_attn<<<dim3(512), dim3(512), 0, stream>>>(HbT, C2, D2b, mb, out);
}

// Round 17
// 127.039 us; speedup vs baseline: 1.7675x; 1.7175x over previous
//
#include <hip/hip_runtime.h>
#include <hip/hip_bf16.h>

typedef unsigned short u16;
typedef __attribute__((ext_vector_type(8))) short short8;
typedef __attribute__((ext_vector_type(2))) float f32x2;
typedef __attribute__((ext_vector_type(4))) float f32x4;
typedef __attribute__((ext_vector_type(16))) float f32x16;

#define N_NODES 4096
#define FIN 512
#define KH 8
#define FO 128
#define DM 1024   // KH*FO
#define LOG2E 1.44269504088896340736f

__device__ __forceinline__ void gload16(const u16* g, u16* l) {
    __builtin_amdgcn_global_load_lds(
        (const __attribute__((address_space(1))) unsigned int*)g,
        (__attribute__((address_space(3))) unsigned int*)l,
        16, 0, 0);
}

__device__ __forceinline__ unsigned pk_bf16(float lo, float hi) {
    unsigned r;
    asm("v_cvt_pk_bf16_f32 %0, %1, %2" : "=v"(r) : "v"(lo), "v"(hi));
    return r;
}

// ---------------- Kernel P: split fp32 -> (hi, lo) bf16 ----------------
__global__ __launch_bounds__(256) void split_bf16(const float* __restrict__ src,
                                                  u16* __restrict__ hi,
                                                  u16* __restrict__ lo,
                                                  int n4) {
    int idx = blockIdx.x * 256 + threadIdx.x;
    if (idx >= n4) return;
    float4 v = ((const float4*)src)[idx];
    unsigned h01 = pk_bf16(v.x, v.y);
    unsigned h23 = pk_bf16(v.z, v.w);
    float hx = __uint_as_float(h01 << 16);
    float hy = __uint_as_float(h01 & 0xffff0000u);
    float hz = __uint_as_float(h23 << 16);
    float hw = __uint_as_float(h23 & 0xffff0000u);
    unsigned l01 = pk_bf16(v.x - hx, v.y - hy);
    unsigned l23 = pk_bf16(v.z - hz, v.w - hw);
    uint2 hv; hv.x = h01; hv.y = h23;
    uint2 lv; lv.x = l01; lv.y = l23;
    ((uint2*)hi)[idx] = hv;
    ((uint2*)lo)[idx] = lv;
}

// ---------------- Kernel A: MFMA split-bf16 GEMM + bias + C/D factor tables + transpose ----
__global__ __launch_bounds__(512) void gemm_mfma(const u16* __restrict__ Xh,
                                                 const u16* __restrict__ Xl,
                                                 const u16* __restrict__ Wh,
                                                 const u16* __restrict__ Wl,
                                                 const float* __restrict__ bias,
                                                 const float* __restrict__ aL,
                                                 const float* __restrict__ aR,
                                                 float2* __restrict__ C2,
                                                 unsigned* __restrict__ D2b,
                                                 u16* __restrict__ HbT) {
    const int khead = blockIdx.x;
    const int n0 = blockIdx.y * 128;
    const int tid = threadIdx.x;
    const int w = tid >> 6, lane = tid & 63;
    const int wr = w >> 1, wc = w & 1;
    const int c = lane & 31, half = lane >> 5;

    __shared__ u16 S[2][16384];

    const int sa = w >> 1;
    const int shv = w & 1;
    const int scl = lane & 3;
    const int ssw = ((lane >> 2) ^ (lane >> 4)) & 3;
    const int sgc = scl ^ ssw;
    const u16* gb; int growbase;
    if (sa == 0)      { gb = Xh; growbase = n0; }
    else if (sa == 1) { gb = Xl; growbase = n0; }
    else if (sa == 2) { gb = Wh; growbase = khead * 128; }
    else              { gb = Wl; growbase = khead * 128; }
    const u16* glb = gb + (size_t)(growbase + shv * 64 + (lane >> 2)) * FIN + sgc * 8;
    const int sldsoff = sa * 4096 + shv * 64 * 32;

    const int sw = ((c) ^ (c >> 2)) & 3;
    const int aoff = (wr * 32 + c) * 32;
    const int boff0 = 8192 + (wc * 64 + c) * 32;
    const int boff1 = 8192 + (wc * 64 + 32 + c) * 32;

    f32x16 acc0, acc1;
#pragma unroll
    for (int i = 0; i < 16; ++i) { acc0[i] = 0.f; acc1[i] = 0.f; }

#pragma unroll
    for (int i = 0; i < 4; ++i)
        gload16(glb + (size_t)i * 16 * FIN, &S[0][sldsoff + i * 512]);
    __syncthreads();

    int cur = 0;
    for (int kt = 0; kt < 16; ++kt) {
        if (kt < 15) {
            const u16* gsrc = glb + (kt + 1) * 32;
            u16* dst = &S[cur ^ 1][sldsoff];
#pragma unroll
            for (int i = 0; i < 4; ++i)
                gload16(gsrc + (size_t)i * 16 * FIN, dst + i * 512);
        }

        const u16* sp = S[cur];
        short8 ah[2], al8[2], bh[2][2], bl8[2][2];
#pragma unroll
        for (int ks = 0; ks < 2; ++ks) {
            int ch = ((ks * 2 + half) ^ sw) * 8;
            ah[ks]     = *(const short8*)&sp[aoff + ch];
            al8[ks]    = *(const short8*)&sp[4096 + aoff + ch];
            bh[0][ks]  = *(const short8*)&sp[boff0 + ch];
            bl8[0][ks] = *(const short8*)&sp[boff0 + 4096 + ch];
            bh[1][ks]  = *(const short8*)&sp[boff1 + ch];
            bl8[1][ks] = *(const short8*)&sp[boff1 + 4096 + ch];
        }
#pragma unroll
        for (int ks = 0; ks < 2; ++ks) {
            acc0 = __builtin_amdgcn_mfma_f32_32x32x16_bf16(ah[ks], bh[0][ks], acc0, 0, 0, 0);
            acc0 = __builtin_amdgcn_mfma_f32_32x32x16_bf16(ah[ks], bl8[0][ks], acc0, 0, 0, 0);
            acc0 = __builtin_amdgcn_mfma_f32_32x32x16_bf16(al8[ks], bh[0][ks], acc0, 0, 0, 0);
            acc1 = __builtin_amdgcn_mfma_f32_32x32x16_bf16(ah[ks], bh[1][ks], acc1, 0, 0, 0);
            acc1 = __builtin_amdgcn_mfma_f32_32x32x16_bf16(ah[ks], bl8[1][ks], acc1, 0, 0, 0);
            acc1 = __builtin_amdgcn_mfma_f32_32x32x16_bf16(al8[ks], bh[1][ks], acc1, 0, 0, 0);
        }
        __syncthreads();
        cur ^= 1;
    }

    const int fglob = khead * FO + wc * 64 + c;
    float b0 = bias[fglob], b1 = bias[fglob + 32];
#pragma unroll
    for (int r = 0; r < 16; ++r) { acc0[r] += b0; acc1[r] += b1; }

    float alv0 = aL[fglob], alv1 = aL[fglob + 32];
    float arv0 = aR[fglob], arv1 = aR[fglob + 32];
    float pl[16], pr[16];
#pragma unroll
    for (int r = 0; r < 16; ++r) {
        pl[r] = acc0[r] * alv0 + acc1[r] * alv1;
        pr[r] = acc0[r] * arv0 + acc1[r] * arv1;
    }
#pragma unroll
    for (int off = 1; off < 32; off <<= 1) {
#pragma unroll
        for (int r = 0; r < 16; ++r) {
            pl[r] += __shfl_xor(pl[r], off);
            pr[r] += __shfl_xor(pr[r], off);
        }
    }

    u16* T = &S[0][0];
    float* LRf = (float*)&S[0][0] + 9216;

    if (c == 0) {
#pragma unroll
        for (int r = 0; r < 16; ++r) {
            int node = wr * 32 + (r & 3) + 8 * (r >> 2) + 4 * half;
            LRf[(wc * 2 + 0) * 128 + node] = pl[r];
            LRf[(wc * 2 + 1) * 128 + node] = pr[r];
        }
    }

#pragma unroll
    for (int q = 0; q < 4; ++q) {
        int nb = wr * 32 + q * 8 + 4 * half;
        unsigned p00 = pk_bf16(acc0[q * 4 + 0], acc0[q * 4 + 1]);
        unsigned p01 = pk_bf16(acc0[q * 4 + 2], acc0[q * 4 + 3]);
        unsigned p10 = pk_bf16(acc1[q * 4 + 0], acc1[q * 4 + 1]);
        unsigned p11 = pk_bf16(acc1[q * 4 + 2], acc1[q * 4 + 3]);
        *(unsigned*)&T[(wc * 64 + c) * 136 + nb]      = p00;
        *(unsigned*)&T[(wc * 64 + c) * 136 + nb + 2]  = p01;
        *(unsigned*)&T[(wc * 64 + 32 + c) * 136 + nb]     = p10;
        *(unsigned*)&T[(wc * 64 + 32 + c) * 136 + nb + 2] = p11;
    }
    __syncthreads();

    // factor tables: C2 = (exp2(L2E*l), exp2(0.2*L2E*l)) fp32; D2b = packed bf16 pair
    if (wc == 0) {
        int node = wr * 32 + (lane & 31);
        if (lane < 32) {
            float L = (LRf[0 * 128 + node] + LRf[2 * 128 + node]) * LOG2E;
            float2 cv; cv.x = exp2f(L); cv.y = exp2f(0.2f * L);
            C2[(size_t)khead * N_NODES + n0 + node] = cv;
        } else {
            float R = (LRf[1 * 128 + node] + LRf[3 * 128 + node]) * LOG2E;
            D2b[(size_t)khead * N_NODES + n0 + node] = pk_bf16(exp2f(R), exp2f(0.2f * R));
        }
    }

    {
        int f = tid >> 2, q = tid & 3;
        const uint4* src = (const uint4*)&T[f * 136 + q * 32];
        uint4* dst = (uint4*)(HbT + (size_t)(khead * FO + f) * N_NODES + n0 + q * 32);
#pragma unroll
        for (int u = 0; u < 4; ++u) dst[u] = src[u];
    }
}

// ---------------- Kernel D: pack mask (int32 0/1) into bitmask ----------------
__global__ __launch_bounds__(256) void pack_mask(const int* __restrict__ mask,
                                                 unsigned long long* __restrict__ mb) {
    int gid = blockIdx.x * 256 + threadIdx.x;
    int wid = gid >> 6, lane = gid & 63;
    int v = mask[(size_t)wid * 64 + lane];
    unsigned long long bits = __ballot(v != 0);
    if (lane == 0) mb[wid] = bits;
}

// ---------------- Kernel C: flash-style masked softmax + PV aggregation ----------------
// R11-proven (best measured, 78.6us): flat grid 512, head = blk&7 (head<->XCD pin).
// ONE barrier per m-tile; stage(t+1) + D(t+1) issued at iteration START; free-scheduled
// compute; tail = lgkm0 + counted vmcnt(5) (retires stage, leaves D in flight) + barrier.
__global__ __launch_bounds__(512, 4) void gat_attn(const u16* __restrict__ HbT,
                                                   const float2* __restrict__ C2,
                                                   const unsigned* __restrict__ D2b,
                                                   const unsigned long long* __restrict__ mb,
                                                   float* __restrict__ out) {
    const int blk = blockIdx.x;
    const int k = blk & 7;
    const int n0 = (blk >> 3) * 64;
    const int tid = threadIdx.x;
    const int w = tid >> 6, lane = tid & 63;
    const int g = w >> 2, wg = w & 3;
    const int fr = lane & 15, kg = lane >> 4;

    __shared__ u16 Ht[2][2][128 * 64];   // [m-group][buf][tile] = 64 KB

    const int n_a = n0 + wg * 16 + fr;
    const float2 ccf = C2[(size_t)k * N_NODES + n_a];
    const float ccx = ccf.x, ccy = ccf.y;
    const unsigned long long* mrow = mb + (size_t)n_a * 64 + g * 32;
    const int shA = kg * 8, shB = shA + 32;

    f32x4 acc[9];
#pragma unroll
    for (int c = 0; c < 9; ++c) acc[c] = 0.f;

    const short o1 = (fr == 0) ? (short)0x3F80 : (short)0;
    const short8 ones = {o1, o1, o1, o1, o1, o1, o1, o1};

    const int fsub = lane >> 3;
    const int seg = ((lane & 7) ^ fsub) * 8;
    const u16* gstage = HbT + (size_t)(k * FO + wg * 32 + fsub) * N_NODES + g * 2048 + seg;
    u16* lb0 = &Ht[g][0][wg * 2048];
    u16* lb1 = &Ht[g][1][wg * 2048];

    const int frx = fr & 7;
    const int off0 = fr * 64 + (kg ^ frx) * 8;
    const int off1 = fr * 64 + ((kg + 4) ^ frx) * 8;

    const unsigned* D2k = D2b + (size_t)k * N_NODES + g * 2048 + kg * 8;

    // ---- prologue: stage(0)->lb0 [4], D(0) [5]; vmcnt(5) retires stage(0); barrier ----
    uint4 dc0, dc1, dc2, dc3;
    unsigned long long bc;
#pragma unroll
    for (int j = 0; j < 4; ++j)
        gload16(gstage + (size_t)j * 8 * N_NODES, lb0 + j * 512);
    dc0 = *(const uint4*)(D2k);      dc1 = *(const uint4*)(D2k + 4);
    dc2 = *(const uint4*)(D2k + 32); dc3 = *(const uint4*)(D2k + 36);
    bc = mrow[0];
    asm volatile("s_waitcnt vmcnt(5)" ::: "memory");
    __builtin_amdgcn_s_barrier();

// One half-iteration: reads RBUF (tile MT, factors DC*/BITS), stages tile MT+1 into
// SBUF, loads D(MT+1) into DN*/NBITS. Free-scheduled compute; counted-vmcnt tail.
#define ATTN_HALF(RBUF, SBUF, MT, DC0,DC1,DC2,DC3,BITS, DN0,DN1,DN2,DN3,NBITS) do {    \
    const unsigned nxt = ((MT) + 1) & 31;                                               \
    if ((MT) < 31) {                                                                    \
        const u16* gs = gstage + ((size_t)nxt << 6);                                    \
        _Pragma("unroll")                                                               \
        for (int j = 0; j < 4; ++j)                                                     \
            gload16(gs + (size_t)j * 8 * N_NODES, (SBUF) + j * 512);                    \
    }                                                                                   \
    { const unsigned* dnp = D2k + (nxt << 6);                                           \
      DN0 = *(const uint4*)(dnp);      DN1 = *(const uint4*)(dnp + 4);                  \
      DN2 = *(const uint4*)(dnp + 32); DN3 = *(const uint4*)(dnp + 36);                 \
      NBITS = mrow[nxt]; }                                                              \
    __builtin_amdgcn_sched_barrier(0);                                                  \
    {                                                                                   \
        unsigned m32a = (unsigned)((BITS) >> shA);                                      \
        unsigned m32b = (unsigned)((BITS) >> shB);                                      \
        unsigned wa[8] = {DC0.x, DC0.y, DC0.z, DC0.w, DC1.x, DC1.y, DC1.z, DC1.w};      \
        unsigned wb[8] = {DC2.x, DC2.y, DC2.z, DC2.w, DC3.x, DC3.y, DC3.z, DC3.w};      \
        float p0[8], p1[8];                                                             \
        _Pragma("unroll")                                                               \
        for (int v = 0; v < 8; ++v) {                                                   \
            float pa = fmaxf(ccx * __uint_as_float(wa[v] << 16),                        \
                             ccy * __uint_as_float(wa[v] & 0xffff0000u));               \
            unsigned sa2 = (unsigned)(((int)(m32a << (31 - v))) >> 31);                 \
            p0[v] = __uint_as_float(__float_as_uint(pa) & sa2);                         \
            float pb = fmaxf(ccx * __uint_as_float(wb[v] << 16),                        \
                             ccy * __uint_as_float(wb[v] & 0xffff0000u));               \
            unsigned sb2 = (unsigned)(((int)(m32b << (31 - v))) >> 31);                 \
            p1[v] = __uint_as_float(__float_as_uint(pb) & sb2);                         \
        }                                                                               \
        union { unsigned u[4]; short8 s; } ua, ub;                                      \
        _Pragma("unroll")                                                               \
        for (int vp = 0; vp < 4; ++vp) {                                                \
            ua.u[vp] = pk_bf16(p0[2 * vp], p0[2 * vp + 1]);                             \
            ub.u[vp] = pk_bf16(p1[2 * vp], p1[2 * vp + 1]);                             \
        }                                                                               \
        short8 a0 = ua.s, a1 = ub.s;                                                    \
        const u16* hb = (RBUF);                                                         \
        __builtin_amdgcn_s_setprio(1);                                                  \
        _Pragma("unroll")                                                               \
        for (int c = 0; c < 8; ++c) {                                                   \
            short8 b0 = *(const short8*)(hb + c * 1024 + off0);                         \
            short8 b1 = *(const short8*)(hb + c * 1024 + off1);                         \
            acc[c] = __builtin_amdgcn_mfma_f32_16x16x32_bf16(a0, b0, acc[c], 0, 0, 0);  \
            acc[c] = __builtin_amdgcn_mfma_f32_16x16x32_bf16(a1, b1, acc[c], 0, 0, 0);  \
        }                                                                               \
        acc[8] = __builtin_amdgcn_mfma_f32_16x16x32_bf16(a0, ones, acc[8], 0, 0, 0);    \
        acc[8] = __builtin_amdgcn_mfma_f32_16x16x32_bf16(a1, ones, acc[8], 0, 0, 0);    \
        __builtin_amdgcn_s_setprio(0);                                                  \
    }                                                                                   \
    asm volatile("s_waitcnt lgkmcnt(0)" ::: "memory");                                  \
    asm volatile("s_waitcnt vmcnt(5)" ::: "memory");                                    \
    __builtin_amdgcn_s_barrier();                                                       \
} while (0)

    {
        uint4 en0, en1, en2, en3;
        unsigned long long bn;
        // Group base LDS pointers for reads (wave reads the whole group tile)
        const u16* rb0 = &Ht[g][0][0];
        const u16* rb1 = &Ht[g][1][0];
        for (int mt = 0; mt < 32; mt += 2) {
            ATTN_HALF(rb0, lb1, mt,     dc0, dc1, dc2, dc3, bc, en0, en1, en2, en3, bn);
            ATTN_HALF(rb1, lb0, mt + 1, en0, en1, en2, en3, bn, dc0, dc1, dc2, dc3, bc);
        }
    }
#undef ATTN_HALF

    asm volatile("s_waitcnt vmcnt(0)" ::: "memory");
    __syncthreads();   // full drain before LDS reuse

    float* cmb = (float*)&Ht[0][0][0];
    if (g == 1) {
        float* base = cmb + wg * (36 * 64);
#pragma unroll
        for (int c = 0; c < 9; ++c)
#pragma unroll
            for (int j = 0; j < 4; ++j) base[(c * 4 + j) * 64 + lane] = acc[c][j];
    }
    __syncthreads();
    if (g == 0) {
        const float* base = cmb + wg * (36 * 64);
#pragma unroll
        for (int c = 0; c < 9; ++c)
#pragma unroll
            for (int j = 0; j < 4; ++j) acc[c][j] += base[(c * 4 + j) * 64 + lane];

#pragma unroll
        for (int j = 0; j < 4; ++j) {
            float S = __shfl(acc[8][j], (lane & 48));
            float inv = 1.0f / S;
            int n_out = n0 + wg * 16 + kg * 4 + j;
            float* orow = out + (size_t)n_out * DM + k * FO + fr;
#pragma unroll
            for (int c = 0; c < 8; ++c) {
                float v = acc[c][j] * inv;
                float e = v > 0.f ? v : (__expf(v) - 1.0f);
                orow[c * 16] = e;
            }
        }
    }
}

extern "C" void kernel_launch(void* const* d_in, const int* in_sizes, int n_in,
                              void* d_out, int out_size, void* d_ws, size_t ws_size,
                              hipStream_t stream) {
    const float* x = (const float*)d_in[0];
    const int* mask = (const int*)d_in[1];
    const float* W = (const float*)d_in[2];
    const float* bias = (const float*)d_in[3];
    const float* aL = (const float*)d_in[4];
    const float* aR = (const float*)d_in[5];
    float* out = (float*)d_out;

    char* ws = (char*)d_ws;
    u16* Xh = (u16*)ws;   ws += (size_t)N_NODES * FIN * 2;   // 4.19 MB
    u16* Xl = (u16*)ws;   ws += (size_t)N_NODES * FIN * 2;   // 4.19 MB
    u16* Wh = (u16*)ws;   ws += (size_t)DM * FIN * 2;        // 1.05 MB
    u16* Wl = (u16*)ws;   ws += (size_t)DM * FIN * 2;        // 1.05 MB
    u16* HbT = (u16*)ws;  ws += (size_t)KH * FO * N_NODES * 2; // 8.39 MB
    float2* C2 = (float2*)ws;  ws += (size_t)KH * N_NODES * 8;  // 256 KB
    unsigned* D2b = (unsigned*)ws; ws += (size_t)KH * N_NODES * 4; // 128 KB
    unsigned long long* mb = (unsigned long long*)ws;        // 2 MB

    split_bf16<<<dim3(2048), dim3(256), 0, stream>>>(x, Xh, Xl, N_NODES * FIN / 4);
    split_bf16<<<dim3(512), dim3(256), 0, stream>>>(W, Wh, Wl, DM * FIN / 4);
    gemm_mfma<<<dim3(8, 32), dim3(512), 0, stream>>>(Xh, Xl, Wh, Wl, bias, aL, aR,
                                                     C2, D2b, HbT);
    pack_mask<<<dim3(65536), dim3(256), 0, stream>>>(mask, mb);
    gat_attn<<<dim3(512), dim3(512), 0, stream>>>(HbT, C2, D2b, mb, out);
}